// Round 2
// baseline (394.080 us; speedup 1.0000x reference)
//
#include <hip/hip_runtime.h>
#include <hip/hip_bf16.h>
#include <cstdint>
#include <cstddef>

#define D_MODEL 1024
#define N_HEADS 16
#define D_STATE 64
#define SEQ 4096
#define BATCH 4
#define M_TOK (BATCH * SEQ)          // 16384 tokens
#define N1 4096                      // fused [Wg | Wp] output width
#define CLEN 128                     // scan chunk length
#define NCH (SEQ / CLEN)             // 32 chunks per sequence
#define NCHAN (BATCH * D_MODEL)      // 4096 scan channels

typedef __attribute__((ext_vector_type(8))) short bf16x8;
typedef __attribute__((ext_vector_type(4))) float f32x4;

__device__ __forceinline__ float sigmoidf_(float x) {
    return 1.0f / (1.0f + __expf(-x));
}

__device__ __forceinline__ void async_load16(const void* g, void* l) {
    __builtin_amdgcn_global_load_lds(
        (__attribute__((address_space(1))) void*)(g),
        (__attribute__((address_space(3))) void*)(l), 16, 0, 0);
}

// ---------------- transpose + fp32->bf16 convert ----------------
__global__ __launch_bounds__(256) void transpose_cvt(
    const float* __restrict__ src, __hip_bfloat16* __restrict__ dst,
    int K, int N)
{
    __shared__ float tile[32][33];
    int n0 = blockIdx.x * 32, k0 = blockIdx.y * 32;
    int tx = threadIdx.x, ty = threadIdx.y;  // 32 x 8
#pragma unroll
    for (int j = 0; j < 32; j += 8)
        tile[ty + j][tx] = src[(size_t)(k0 + ty + j) * N + n0 + tx];
    __syncthreads();
#pragma unroll
    for (int j = 0; j < 32; j += 8)
        dst[(size_t)(n0 + ty + j) * K + k0 + tx] = __float2bfloat16(tile[tx][ty + j]);
}

// ---------------- RMSNorm -> bf16 ----------------
__global__ __launch_bounds__(256) void rmsnorm_kernel(
    const float* __restrict__ x, const float* __restrict__ w,
    __hip_bfloat16* __restrict__ xn)
{
    int m = blockIdx.x;
    int tid = threadIdx.x;
    const float4* xr = (const float4*)(x + (size_t)m * D_MODEL);
    float4 v = xr[tid];
    float ss = v.x * v.x + v.y * v.y + v.z * v.z + v.w * v.w;
#pragma unroll
    for (int o = 32; o >= 1; o >>= 1) ss += __shfl_xor(ss, o, 64);
    __shared__ float red[4];
    int wave = tid >> 6, lane = tid & 63;
    if (lane == 0) red[wave] = ss;
    __syncthreads();
    float tot = red[0] + red[1] + red[2] + red[3];
    float scale = rsqrtf(tot * (1.0f / D_MODEL) + 1e-6f);
    const float4* wr = (const float4*)w;
    float4 wv = wr[tid];
    __hip_bfloat16 o4[4];
    o4[0] = __float2bfloat16(wv.x * v.x * scale);
    o4[1] = __float2bfloat16(wv.y * v.y * scale);
    o4[2] = __float2bfloat16(wv.z * v.z * scale);
    o4[3] = __float2bfloat16(wv.w * v.w * scale);
    *(uint64_t*)(xn + (size_t)m * D_MODEL + tid * 4) = *(uint64_t*)o4;
}

// ---------------- 256x256 8-phase-interleaved bf16 MFMA GEMM ----------------
// C = A(M,K) * Bt(N,K)^T, 512 threads = 8 waves (2M x 4N), BK=64.
// LDS 128 KiB: 2 dbuf x (A 256x64 + B 256x64) bf16.
// T2: 16B-slot XOR swizzle, linear LDS dest + inverse-swizzled global src
//     + swizzled ds_read (both-sides involution) -> 0 bank conflicts (R1).
// T3+T4 (m201-faithful): per-phase stage interleave. Tile t+1's 8 chunk
//     loads issue 2-per-phase during tile t (into the buffer freed at end
//     of t-1). Chunk consumption: P0 needs {a0,a2,b0..b3}, P2 needs
//     {a1,a3} -> issue order b0,b1 | b2,b3 | a0,a2 | a1,a3. Counted
//     waits, never 0 mid-loop: vmcnt(4) end-of-P1 (own a1,a3 landed),
//     vmcnt(2) in P3 (t+1's first 6 chunks landed). Each wait precedes a
//     barrier so cross-wave deposits are visible before dependent ds_reads.
// T5: setprio(1) around each 16-MFMA cluster; sched_barrier(0) pins phases.
// MODE 0: out bf16, bias = (col<1024 ? bias0[col] : bias1[col-1024])
// MODE 1: out fp32, bias = bias0[col] + bias1[row*1024+col] (residual)

template <int MODE>
__global__ __launch_bounds__(512, 2) void gemm256(
    const __hip_bfloat16* __restrict__ A,
    const __hip_bfloat16* __restrict__ Bt,
    const float* __restrict__ bias0,
    const float* __restrict__ bias1,
    void* __restrict__ outp, int N, int K)
{
    extern __shared__ short lds[];
    const int tid = threadIdx.x;
    const int wave = tid >> 6, lane = tid & 63;
    const int fr = lane & 15, fq = lane >> 4;
    const int frx = fr & 7;
    const int wm = (wave >> 2) * 128;   // 2 M-halves of waves
    const int wn = (wave & 3) * 64;     // 4 N-quarters

    // bijective XCD swizzle (nwg % 8 == 0 for both modes)
    const int gx = gridDim.x;
    const int nwg = gx * gridDim.y;
    const int orig = blockIdx.y * gx + blockIdx.x;
    const int swz = (orig & 7) * (nwg >> 3) + (orig >> 3);
    const int m0 = (swz / gx) * 256;
    const int n0 = (swz % gx) * 256;

    // staging map: thread t -> row rb (8 threads/row), 16B slot p8.
    // global source slot is pre-inverse-swizzled so LDS dest stays linear.
    const int rb = tid >> 3, p8 = tid & 7;
    const int lsl = p8 ^ (rb & 7);
    const short* Ag0 = (const short*)A + (size_t)(m0 + rb) * K + lsl * 8;
    const short* Bg0 = (const short*)Bt + (size_t)(n0 + rb) * K + lsl * 8;
    const int stL = rb * 64 + p8 * 8;   // shorts; == wave-uniform + lane*16B

    const int NT = K >> 6;              // K-tiles of 64

    f32x4 acc[2][4][4];
#pragma unroll
    for (int h = 0; h < 2; ++h)
#pragma unroll
        for (int i = 0; i < 4; ++i)
#pragma unroll
            for (int j = 0; j < 4; ++j)
                acc[h][i][j] = (f32x4){0.f, 0.f, 0.f, 0.f};

    // prologue: stage tile 0 -> buf0, issue order B0,B1,B2,B3,A0,A2,A1,A3
    {
        short* la = lds;
        short* lb = lds + 16384;
        async_load16(Bg0 + (size_t)(0 * 64) * K, lb + stL + 0 * 4096);
        async_load16(Bg0 + (size_t)(1 * 64) * K, lb + stL + 1 * 4096);
        async_load16(Bg0 + (size_t)(2 * 64) * K, lb + stL + 2 * 4096);
        async_load16(Bg0 + (size_t)(3 * 64) * K, lb + stL + 3 * 4096);
        async_load16(Ag0 + (size_t)(0 * 64) * K, la + stL + 0 * 4096);
        async_load16(Ag0 + (size_t)(2 * 64) * K, la + stL + 2 * 4096);
        async_load16(Ag0 + (size_t)(1 * 64) * K, la + stL + 1 * 4096);
        async_load16(Ag0 + (size_t)(3 * 64) * K, la + stL + 3 * 4096);
    }
    asm volatile("s_waitcnt vmcnt(2)" ::: "memory");  // first 6 chunks landed
    __builtin_amdgcn_s_barrier();
    __builtin_amdgcn_sched_barrier(0);

// swizzled fragment reads: phys slot = (kk*4+fq) ^ (row&7); row&7 == fr&7
#define LDA(h, i, kk) (*(const bf16x8*)&Ab[(wm + (h)*64 + (i)*16 + fr) * 64 + \
                                           (((kk)*4 + fq) ^ frx) * 8])
#define LDB(j, kk)    (*(const bf16x8*)&Bb[(wn + (j)*16 + fr) * 64 + \
                                           (((kk)*4 + fq) ^ frx) * 8])
#define STAGE_A(c) async_load16(AgN + (size_t)((c) * 64) * K, laN + stL + (c) * 4096)
#define STAGE_B(c) async_load16(BgN + (size_t)((c) * 64) * K, lbN + stL + (c) * 4096)

    for (int t = 0; t < NT; ++t) {
        const short* Ab = lds + ((t & 1) ? 32768 : 0);
        const short* Bb = Ab + 16384;
        short* laN = lds + ((t & 1) ? 0 : 32768);
        short* lbN = laN + 16384;
        const short* AgN = Ag0 + (size_t)(t + 1) * 64;
        const short* BgN = Bg0 + (size_t)(t + 1) * 64;
        const bool pf = (t + 1 < NT);

        bf16x8 af[4][2], b0[2][2], b1[2][2];

        // ---- P0: M-half0 x N-frags 0..1 ; stage t+1 chunks b0,b1 ----
#pragma unroll
        for (int i = 0; i < 4; ++i) { af[i][0] = LDA(0, i, 0); af[i][1] = LDA(0, i, 1); }
#pragma unroll
        for (int j = 0; j < 2; ++j) { b0[j][0] = LDB(j, 0); b0[j][1] = LDB(j, 1); }
        if (pf) { STAGE_B(0); STAGE_B(1); }
        __builtin_amdgcn_s_barrier();
        __builtin_amdgcn_sched_barrier(0);
        __builtin_amdgcn_s_setprio(1);
#pragma unroll
        for (int i = 0; i < 4; ++i)
#pragma unroll
            for (int j = 0; j < 2; ++j) {
                acc[0][i][j] = __builtin_amdgcn_mfma_f32_16x16x32_bf16(af[i][0], b0[j][0], acc[0][i][j], 0, 0, 0);
                acc[0][i][j] = __builtin_amdgcn_mfma_f32_16x16x32_bf16(af[i][1], b0[j][1], acc[0][i][j], 0, 0, 0);
            }
        __builtin_amdgcn_s_setprio(0);
        __builtin_amdgcn_sched_barrier(0);
        __builtin_amdgcn_s_barrier();
        __builtin_amdgcn_sched_barrier(0);

        // ---- P1: M-half0 x N-frags 2..3 ; stage t+1 chunks b2,b3 ----
#pragma unroll
        for (int j = 0; j < 2; ++j) { b1[j][0] = LDB(2 + j, 0); b1[j][1] = LDB(2 + j, 1); }
        if (pf) { STAGE_B(2); STAGE_B(3); }
        __builtin_amdgcn_s_barrier();
        __builtin_amdgcn_sched_barrier(0);
        __builtin_amdgcn_s_setprio(1);
#pragma unroll
        for (int i = 0; i < 4; ++i)
#pragma unroll
            for (int j = 0; j < 2; ++j) {
                acc[0][i][2 + j] = __builtin_amdgcn_mfma_f32_16x16x32_bf16(af[i][0], b1[j][0], acc[0][i][2 + j], 0, 0, 0);
                acc[0][i][2 + j] = __builtin_amdgcn_mfma_f32_16x16x32_bf16(af[i][1], b1[j][1], acc[0][i][2 + j], 0, 0, 0);
            }
        __builtin_amdgcn_s_setprio(0);
        __builtin_amdgcn_sched_barrier(0);
        // counted wait: own a1,a3 (oldest outstanding) landed; t+1's 4 B
        // loads stay in flight. Barrier below makes deposits wave-global.
        if (pf) { asm volatile("s_waitcnt vmcnt(4)" ::: "memory"); }
        else    { asm volatile("s_waitcnt vmcnt(0)" ::: "memory"); }
        __builtin_amdgcn_s_barrier();
        __builtin_amdgcn_sched_barrier(0);

        // ---- P2: M-half1 x N-frags 0..1 (reuse b0) ; stage a0,a2 ----
#pragma unroll
        for (int i = 0; i < 4; ++i) { af[i][0] = LDA(1, i, 0); af[i][1] = LDA(1, i, 1); }
        if (pf) { STAGE_A(0); STAGE_A(2); }
        __builtin_amdgcn_s_barrier();
        __builtin_amdgcn_sched_barrier(0);
        __builtin_amdgcn_s_setprio(1);
#pragma unroll
        for (int i = 0; i < 4; ++i)
#pragma unroll
            for (int j = 0; j < 2; ++j) {
                acc[1][i][j] = __builtin_amdgcn_mfma_f32_16x16x32_bf16(af[i][0], b0[j][0], acc[1][i][j], 0, 0, 0);
                acc[1][i][j] = __builtin_amdgcn_mfma_f32_16x16x32_bf16(af[i][1], b0[j][1], acc[1][i][j], 0, 0, 0);
            }
        __builtin_amdgcn_s_setprio(0);
        __builtin_amdgcn_sched_barrier(0);
        __builtin_amdgcn_s_barrier();
        __builtin_amdgcn_sched_barrier(0);

        // ---- P3: M-half1 x N-frags 2..3 (reuse af,b1) ; stage a1,a3 ----
        if (pf) {
            STAGE_A(1); STAGE_A(3);
            // t+1's first 6 chunks (b0..b3,a0,a2) landed; its a1,a3 in
            // flight. Barrier below covers next tile's P0 ds_reads.
            asm volatile("s_waitcnt vmcnt(2)" ::: "memory");
        }
        __builtin_amdgcn_s_barrier();
        __builtin_amdgcn_sched_barrier(0);
        __builtin_amdgcn_s_setprio(1);
#pragma unroll
        for (int i = 0; i < 4; ++i)
#pragma unroll
            for (int j = 0; j < 2; ++j) {
                acc[1][i][2 + j] = __builtin_amdgcn_mfma_f32_16x16x32_bf16(af[i][0], b1[j][0], acc[1][i][2 + j], 0, 0, 0);
                acc[1][i][2 + j] = __builtin_amdgcn_mfma_f32_16x16x32_bf16(af[i][1], b1[j][1], acc[1][i][2 + j], 0, 0, 0);
            }
        __builtin_amdgcn_s_setprio(0);
        __builtin_amdgcn_sched_barrier(0);
        __builtin_amdgcn_s_barrier();
        __builtin_amdgcn_sched_barrier(0);
    }
#undef LDA
#undef LDB
#undef STAGE_A
#undef STAGE_B

    // epilogue: C/D layout row=fq*4+r, col=fr within 16x16 (m89-verified)
    if constexpr (MODE == 0) {
        __hip_bfloat16* O = (__hip_bfloat16*)outp;
        float bv[4];
#pragma unroll
        for (int j = 0; j < 4; ++j) {
            int gcol = n0 + wn + j * 16 + fr;
            bv[j] = (gcol < D_MODEL) ? bias0[gcol] : bias1[gcol - D_MODEL];
        }
#pragma unroll
        for (int h = 0; h < 2; ++h)
#pragma unroll
            for (int i = 0; i < 4; ++i)
#pragma unroll
                for (int r = 0; r < 4; ++r) {
                    int grow = m0 + wm + h * 64 + i * 16 + fq * 4 + r;
                    __hip_bfloat16* orow = O + (size_t)grow * N + n0 + wn + fr;
#pragma unroll
                    for (int j = 0; j < 4; ++j)
                        orow[j * 16] = __float2bfloat16(acc[h][i][j][r] + bv[j]);
                }
    } else {
        float* O = (float*)outp;
#pragma unroll
        for (int h = 0; h < 2; ++h)
#pragma unroll
            for (int i = 0; i < 4; ++i)
#pragma unroll
                for (int r = 0; r < 4; ++r) {
                    int grow = m0 + wm + h * 64 + i * 16 + fq * 4 + r;
#pragma unroll
                    for (int j = 0; j < 4; ++j) {
                        int gcol = n0 + wn + j * 16 + fr;
                        O[(size_t)grow * N + gcol] =
                            acc[h][i][j][r] + bias0[gcol] + bias1[(size_t)grow * D_MODEL + gcol];
                    }
                }
    }
}

// ---------------- chunked scan, pass 1 ----------------
__global__ __launch_bounds__(256) void scan_part1(
    const __hip_bfloat16* __restrict__ out1,
    float* __restrict__ Abuf, float* __restrict__ Bbuf)
{
    int g = blockIdx.x * 256 + threadIdx.x;
    int chan = g & (NCHAN - 1);
    int c = g >> 12;
    int b = chan >> 10;
    int hd = chan & 1023;
    int h = hd >> 6, d = hd & 63;
    size_t tok0 = (size_t)b * SEQ + (size_t)c * CLEN;
    const __hip_bfloat16* pd = out1 + tok0 * N1 + D_MODEL + h * 192 + d;
    float a = 1.0f, hloc = 0.0f;
#pragma unroll 4
    for (int s = 0; s < CLEN; s++) {
        float dp = __bfloat162float(pd[0]);
        float bt = __bfloat162float(pd[64]);
        float sd = sigmoidf_(dp);
        a *= sd;
        hloc = sd * hloc + bt;
        pd += N1;
    }
    Abuf[c * NCHAN + chan] = a;
    Bbuf[c * NCHAN + chan] = hloc;
}

// ---------------- scan, pass 2 ----------------
__global__ __launch_bounds__(256) void scan_comb(
    const float* __restrict__ Abuf, const float* __restrict__ Bbuf,
    const float* __restrict__ state, float* __restrict__ Pbuf,
    float* __restrict__ new_state)
{
    int chan = blockIdx.x * 256 + threadIdx.x;
    float hp = state[chan];
#pragma unroll
    for (int c = 0; c < NCH; c++) {
        Pbuf[c * NCHAN + chan] = hp;
        hp = Abuf[c * NCHAN + chan] * hp + Bbuf[c * NCHAN + chan];
    }
    new_state[chan] = hp;
}

// ---------------- scan, pass 3 ----------------
__global__ __launch_bounds__(256) void scan_apply(
    const __hip_bfloat16* __restrict__ out1,
    const __hip_bfloat16* __restrict__ xn,
    const float* __restrict__ Pbuf,
    __hip_bfloat16* __restrict__ mixed)
{
    int g = blockIdx.x * 256 + threadIdx.x;
    int chan = g & (NCHAN - 1);
    int c = g >> 12;
    int b = chan >> 10;
    int hd = chan & 1023;
    int h = hd >> 6, d = hd & 63;
    size_t tok0 = (size_t)b * SEQ + (size_t)c * CLEN;
    const __hip_bfloat16* rbase = out1 + tok0 * N1;
    const __hip_bfloat16* xbase = xn + tok0 * D_MODEL + hd;
    __hip_bfloat16* mbase = mixed + tok0 * D_MODEL + hd;
    const int pcol = D_MODEL + h * 192 + d;
    float hh = Pbuf[c * NCHAN + chan];
#pragma unroll 4
    for (int s = 0; s < CLEN; s++) {
        const __hip_bfloat16* r = rbase + (size_t)s * N1;
        float dp = __bfloat162float(r[pcol]);
        float bt = __bfloat162float(r[pcol + 64]);
        float ct = __bfloat162float(r[pcol + 128]);
        float gp = __bfloat162float(r[hd]);
        float sd = sigmoidf_(dp);
        hh = sd * hh + bt;
        float gg = sigmoidf_(gp);
        float xv = __bfloat162float(xbase[(size_t)s * D_MODEL]);
        mbase[(size_t)s * D_MODEL] = __float2bfloat16(gg * (ct * hh) + (1.0f - gg) * xv);
    }
}

extern "C" void kernel_launch(void* const* d_in, const int* in_sizes, int n_in,
                              void* d_out, int out_size, void* d_ws, size_t ws_size,
                              hipStream_t stream) {
    const float* x      = (const float*)d_in[0];
    const float* state  = (const float*)d_in[1];
    const float* norm_w = (const float*)d_in[2];
    const float* Wp     = (const float*)d_in[3];
    const float* bp     = (const float*)d_in[4];
    const float* Wg     = (const float*)d_in[5];
    const float* bg     = (const float*)d_in[6];
    const float* Wo     = (const float*)d_in[7];
    const float* bo     = (const float*)d_in[8];
    float* out = (float*)d_out;

    // workspace layout (~204 MB)
    __hip_bfloat16* W1T   = (__hip_bfloat16*)d_ws;                  // 4096 x 1024
    __hip_bfloat16* WoT   = W1T + (size_t)N1 * D_MODEL;             // 1024 x 1024
    __hip_bfloat16* xnb   = WoT + (size_t)D_MODEL * D_MODEL;        // 16384 x 1024
    __hip_bfloat16* out1  = xnb + (size_t)M_TOK * D_MODEL;          // 16384 x 4096
    __hip_bfloat16* mixed = out1 + (size_t)M_TOK * N1;              // 16384 x 1024
    float* Abuf = (float*)(mixed + (size_t)M_TOK * D_MODEL);
    float* Bbuf = Abuf + (size_t)NCHAN * NCH;
    float* Pbuf = Bbuf + (size_t)NCHAN * NCH;

    static bool attr_set = false;
    if (!attr_set) {
        hipFuncSetAttribute(reinterpret_cast<const void*>(&gemm256<0>),
                            hipFuncAttributeMaxDynamicSharedMemorySize, 131072);
        hipFuncSetAttribute(reinterpret_cast<const void*>(&gemm256<1>),
                            hipFuncAttributeMaxDynamicSharedMemorySize, 131072);
        attr_set = true;
    }

    dim3 tb(32, 8);
    transpose_cvt<<<dim3(1024 / 32, 1024 / 32), tb, 0, stream>>>(Wg, W1T, 1024, 1024);
    transpose_cvt<<<dim3(3072 / 32, 1024 / 32), tb, 0, stream>>>(
        Wp, W1T + (size_t)D_MODEL * D_MODEL, 1024, 3072);
    transpose_cvt<<<dim3(1024 / 32, 1024 / 32), tb, 0, stream>>>(Wo, WoT, 1024, 1024);

    rmsnorm_kernel<<<M_TOK, 256, 0, stream>>>(x, norm_w, xnb);

    gemm256<0><<<dim3(N1 / 256, M_TOK / 256), 512, 131072, stream>>>(
        xnb, W1T, bg, bp, (void*)out1, N1, D_MODEL);

    scan_part1<<<(NCHAN * NCH) / 256, 256, 0, stream>>>(out1, Abuf, Bbuf);
    scan_comb<<<NCHAN / 256, 256, 0, stream>>>(
        Abuf, Bbuf, state, Pbuf, out + (size_t)M_TOK * D_MODEL);
    scan_apply<<<(NCHAN * NCH) / 256, 256, 0, stream>>>(out1, xnb, Pbuf, mixed);

    gemm256<1><<<dim3(D_MODEL / 256, M_TOK / 256), 512, 131072, stream>>>(
        mixed, WoT, bo, x, (void*)out, D_MODEL, D_MODEL);
}

// Round 4
// 391.449 us; speedup vs baseline: 1.0067x; 1.0067x over previous
//
#include <hip/hip_runtime.h>
#include <hip/hip_bf16.h>
#include <cstdint>
#include <cstddef>

#define D_MODEL 1024
#define N_HEADS 16
#define D_STATE 64
#define SEQ 4096
#define BATCH 4
#define M_TOK (BATCH * SEQ)          // 16384 tokens
#define N1 4096                      // fused [Wg | Wp] output width
#define CLEN 128                     // scan chunk length
#define NCH (SEQ / CLEN)             // 32 chunks per sequence
#define NCHAN (BATCH * D_MODEL)      // 4096 scan channels

typedef __attribute__((ext_vector_type(8))) short bf16x8;
typedef __attribute__((ext_vector_type(4))) float f32x4;

__device__ __forceinline__ float sigmoidf_(float x) {
    return 1.0f / (1.0f + __expf(-x));
}

__device__ __forceinline__ void async_load16(const void* g, void* l) {
    __builtin_amdgcn_global_load_lds(
        (__attribute__((address_space(1))) void*)(g),
        (__attribute__((address_space(3))) void*)(l), 16, 0, 0);
}

// ---------------- transpose + fp32->bf16 convert ----------------
__global__ __launch_bounds__(256) void transpose_cvt(
    const float* __restrict__ src, __hip_bfloat16* __restrict__ dst,
    int K, int N)
{
    __shared__ float tile[32][33];
    int n0 = blockIdx.x * 32, k0 = blockIdx.y * 32;
    int tx = threadIdx.x, ty = threadIdx.y;  // 32 x 8
#pragma unroll
    for (int j = 0; j < 32; j += 8)
        tile[ty + j][tx] = src[(size_t)(k0 + ty + j) * N + n0 + tx];
    __syncthreads();
#pragma unroll
    for (int j = 0; j < 32; j += 8)
        dst[(size_t)(n0 + ty + j) * K + k0 + tx] = __float2bfloat16(tile[tx][ty + j]);
}

// ---------------- RMSNorm -> bf16 ----------------
__global__ __launch_bounds__(256) void rmsnorm_kernel(
    const float* __restrict__ x, const float* __restrict__ w,
    __hip_bfloat16* __restrict__ xn)
{
    int m = blockIdx.x;
    int tid = threadIdx.x;
    const float4* xr = (const float4*)(x + (size_t)m * D_MODEL);
    float4 v = xr[tid];
    float ss = v.x * v.x + v.y * v.y + v.z * v.z + v.w * v.w;
#pragma unroll
    for (int o = 32; o >= 1; o >>= 1) ss += __shfl_xor(ss, o, 64);
    __shared__ float red[4];
    int wave = tid >> 6, lane = tid & 63;
    if (lane == 0) red[wave] = ss;
    __syncthreads();
    float tot = red[0] + red[1] + red[2] + red[3];
    float scale = rsqrtf(tot * (1.0f / D_MODEL) + 1e-6f);
    const float4* wr = (const float4*)w;
    float4 wv = wr[tid];
    __hip_bfloat16 o4[4];
    o4[0] = __float2bfloat16(wv.x * v.x * scale);
    o4[1] = __float2bfloat16(wv.y * v.y * scale);
    o4[2] = __float2bfloat16(wv.z * v.z * scale);
    o4[3] = __float2bfloat16(wv.w * v.w * scale);
    *(uint64_t*)(xn + (size_t)m * D_MODEL + tid * 4) = *(uint64_t*)o4;
}

// ---------------- 256x256 read-ahead pipelined bf16 MFMA GEMM ----------------
// (Resubmission of R3 — prior bench failed at container level with no
// counters; kernel re-audited: uniform barriers, gate counts verified,
// buffer-overwrite protocol race-free. Source unchanged.)
//
// C = A(M,K) * Bt(N,K)^T, 512 threads = 8 waves (2M x 4N), BK=64.
// LDS 128 KiB: 2 dbuf x (A 256x64 + B 256x64) bf16.
//
// R3 theory: R1/R2 serialized ds_read (2313 cy/CU/tile) with MFMA
// (2483 cy) because reads(P) -> barrier -> MFMA(P). Fix: per-wave
// read-ahead by ONE phase — each phase = {stage; [gate]; issue reads
// for P+1; MFMA(P)@prio1}. The MFMA cluster has no dependency on the
// just-issued reads, so they fly under it; the compiler's lgkm wait
// lands before the NEXT cluster. Only 2 barriers/tile (the vmcnt gates).
//
// Phase->fragment map (per wave): A-h0 used P0,P1; A-h1 used P2,P3;
// b0 used P0,P2; b1 used P1,P3.
// Reads:  P0 issues b1(t);  P1 gate vmcnt(4) then issues afB=h1(t);
//         P2 issues nothing; P3 gate vmcnt(2) then issues afA=h0(t+1),
//         b0(t+1) from the just-staged buffer.
// Stages (tile t+1): P0: B-chunks 0,1 | P1: B 2,3 | P2: A 0,2 | P3: A 1,3.
// Gate counts (per-wave outstanding, oldest-first):
//   P1 gate: {a1,a3(t), b0..b3(t+1)}=6 -> vmcnt(4) lands a1,a3(t).
//   P3 gate: {b0..b3(t+1),a0,a2(t+1),a1,a3(t+1)}=8 -> vmcnt(2) lands
//            first 6 of t+1 (covers h0 + b0 reads). Never 0 mid-loop.
// Buffer safety: all buf(t-1) ds_reads are lgkm-drained by their
// consuming MFMAs before any wave passes gate P3(t-1), so staging into
// buf(t+1)=buf(t-1) at P0(t) is race-free.
// T2 swizzle unchanged (0 conflicts in R1/R2). T1 XCD swizzle unchanged.
// MODE 0: out bf16, bias = (col<1024 ? bias0[col] : bias1[col-1024])
// MODE 1: out fp32, bias = bias0[col] + bias1[row*1024+col] (residual)

template <int MODE>
__global__ __launch_bounds__(512, 2) void gemm256(
    const __hip_bfloat16* __restrict__ A,
    const __hip_bfloat16* __restrict__ Bt,
    const float* __restrict__ bias0,
    const float* __restrict__ bias1,
    void* __restrict__ outp, int N, int K)
{
    extern __shared__ short lds[];
    const int tid = threadIdx.x;
    const int wave = tid >> 6, lane = tid & 63;
    const int fr = lane & 15, fq = lane >> 4;
    const int frx = fr & 7;
    const int wm = (wave >> 2) * 128;   // 2 M-halves of waves
    const int wn = (wave & 3) * 64;     // 4 N-quarters

    // bijective XCD swizzle (nwg % 8 == 0 for both modes)
    const int gx = gridDim.x;
    const int nwg = gx * gridDim.y;
    const int orig = blockIdx.y * gx + blockIdx.x;
    const int swz = (orig & 7) * (nwg >> 3) + (orig >> 3);
    const int m0 = (swz / gx) * 256;
    const int n0 = (swz % gx) * 256;

    // staging map: thread t -> row rb (8 threads/row), 16B slot p8.
    // global source slot is pre-inverse-swizzled so LDS dest stays linear.
    const int rb = tid >> 3, p8 = tid & 7;
    const int lsl = p8 ^ (rb & 7);
    const short* Ag0 = (const short*)A + (size_t)(m0 + rb) * K + lsl * 8;
    const short* Bg0 = (const short*)Bt + (size_t)(n0 + rb) * K + lsl * 8;
    const int stL = rb * 64 + p8 * 8;   // shorts; == wave-uniform + lane*16B

    const int NT = K >> 6;              // K-tiles of 64

    f32x4 acc[2][4][4];
#pragma unroll
    for (int h = 0; h < 2; ++h)
#pragma unroll
        for (int i = 0; i < 4; ++i)
#pragma unroll
            for (int j = 0; j < 4; ++j)
                acc[h][i][j] = (f32x4){0.f, 0.f, 0.f, 0.f};

    // prologue: stage tile 0 -> buf0, issue order B0,B1,B2,B3,A0,A2,A1,A3
    {
        short* la = lds;
        short* lb = lds + 16384;
        async_load16(Bg0 + (size_t)(0 * 64) * K, lb + stL + 0 * 4096);
        async_load16(Bg0 + (size_t)(1 * 64) * K, lb + stL + 1 * 4096);
        async_load16(Bg0 + (size_t)(2 * 64) * K, lb + stL + 2 * 4096);
        async_load16(Bg0 + (size_t)(3 * 64) * K, lb + stL + 3 * 4096);
        async_load16(Ag0 + (size_t)(0 * 64) * K, la + stL + 0 * 4096);
        async_load16(Ag0 + (size_t)(2 * 64) * K, la + stL + 2 * 4096);
        async_load16(Ag0 + (size_t)(1 * 64) * K, la + stL + 1 * 4096);
        async_load16(Ag0 + (size_t)(3 * 64) * K, la + stL + 3 * 4096);
    }
    asm volatile("s_waitcnt vmcnt(2)" ::: "memory");  // b0..b3,a0,a2 landed
    __builtin_amdgcn_s_barrier();
    __builtin_amdgcn_sched_barrier(0);

// swizzled fragment reads: phys slot = (kk*4+fq) ^ (row&7); row&7 == fr&7
#define LDA_(base, h, i, kk) (*(const bf16x8*)&(base)[(wm + (h)*64 + (i)*16 + fr) * 64 + \
                                                      (((kk)*4 + fq) ^ frx) * 8])
#define LDB_(base, j, kk)    (*(const bf16x8*)&(base)[(wn + (j)*16 + fr) * 64 + \
                                                      (((kk)*4 + fq) ^ frx) * 8])
#define STAGE_A(c) async_load16(AgN + (size_t)((c) * 64) * K, laN + stL + (c) * 4096)
#define STAGE_B(c) async_load16(BgN + (size_t)((c) * 64) * K, lbN + stL + (c) * 4096)

    bf16x8 afA[4][2], afB[4][2], b0[2][2], b1[2][2];

    // initial reads for tile 0 / phase P0: A-h0 + b0
    {
        const short* Ab = lds;
        const short* Bb = lds + 16384;
#pragma unroll
        for (int i = 0; i < 4; ++i) { afA[i][0] = LDA_(Ab, 0, i, 0); afA[i][1] = LDA_(Ab, 0, i, 1); }
#pragma unroll
        for (int j = 0; j < 2; ++j) { b0[j][0] = LDB_(Bb, j, 0); b0[j][1] = LDB_(Bb, j, 1); }
    }

    for (int t = 0; t < NT; ++t) {
        const short* Ab = lds + ((t & 1) ? 32768 : 0);
        const short* Bb = Ab + 16384;
        short* laN = lds + ((t & 1) ? 0 : 32768);
        short* lbN = laN + 16384;
        const short* AgN = Ag0 + (size_t)(t + 1) * 64;
        const short* BgN = Bg0 + (size_t)(t + 1) * 64;
        const bool pf = (t + 1 < NT);

        // ---- P0: MFMA h0 x b0 ; stage B0,B1(t+1) ; read-ahead b1(t) ----
        if (pf) { STAGE_B(0); STAGE_B(1); }
#pragma unroll
        for (int j = 0; j < 2; ++j) { b1[j][0] = LDB_(Bb, 2 + j, 0); b1[j][1] = LDB_(Bb, 2 + j, 1); }
        __builtin_amdgcn_s_setprio(1);
#pragma unroll
        for (int i = 0; i < 4; ++i)
#pragma unroll
            for (int j = 0; j < 2; ++j) {
                acc[0][i][j] = __builtin_amdgcn_mfma_f32_16x16x32_bf16(afA[i][0], b0[j][0], acc[0][i][j], 0, 0, 0);
                acc[0][i][j] = __builtin_amdgcn_mfma_f32_16x16x32_bf16(afA[i][1], b0[j][1], acc[0][i][j], 0, 0, 0);
            }
        __builtin_amdgcn_s_setprio(0);
        __builtin_amdgcn_sched_barrier(0);

        // ---- P1: MFMA h0 x b1 ; stage B2,B3(t+1) ; gate ; read-ahead afB ----
        if (pf) { STAGE_B(2); STAGE_B(3); }
        if (pf) { asm volatile("s_waitcnt vmcnt(4)" ::: "memory"); }  // a1,a3(t) landed
        else    { asm volatile("s_waitcnt vmcnt(0)" ::: "memory"); }
        __builtin_amdgcn_s_barrier();   // make all waves' a1,a3 deposits visible
        __builtin_amdgcn_sched_barrier(0);
#pragma unroll
        for (int i = 0; i < 4; ++i) { afB[i][0] = LDA_(Ab, 1, i, 0); afB[i][1] = LDA_(Ab, 1, i, 1); }
        __builtin_amdgcn_s_setprio(1);
#pragma unroll
        for (int i = 0; i < 4; ++i)
#pragma unroll
            for (int j = 0; j < 2; ++j) {
                acc[0][i][2 + j] = __builtin_amdgcn_mfma_f32_16x16x32_bf16(afA[i][0], b1[j][0], acc[0][i][2 + j], 0, 0, 0);
                acc[0][i][2 + j] = __builtin_amdgcn_mfma_f32_16x16x32_bf16(afA[i][1], b1[j][1], acc[0][i][2 + j], 0, 0, 0);
            }
        __builtin_amdgcn_s_setprio(0);
        __builtin_amdgcn_sched_barrier(0);

        // ---- P2: MFMA h1 x b0 ; stage A0,A2(t+1) ----
        if (pf) { STAGE_A(0); STAGE_A(2); }
        __builtin_amdgcn_s_setprio(1);
#pragma unroll
        for (int i = 0; i < 4; ++i)
#pragma unroll
            for (int j = 0; j < 2; ++j) {
                acc[1][i][j] = __builtin_amdgcn_mfma_f32_16x16x32_bf16(afB[i][0], b0[j][0], acc[1][i][j], 0, 0, 0);
                acc[1][i][j] = __builtin_amdgcn_mfma_f32_16x16x32_bf16(afB[i][1], b0[j][1], acc[1][i][j], 0, 0, 0);
            }
        __builtin_amdgcn_s_setprio(0);
        __builtin_amdgcn_sched_barrier(0);

        // ---- P3: MFMA h1 x b1 ; stage A1,A3(t+1) ; gate ; read-ahead
        //          next tile's afA(h0) + b0 from the freshly staged buffer ----
        if (pf) {
            STAGE_A(1); STAGE_A(3);
            asm volatile("s_waitcnt vmcnt(2)" ::: "memory");  // t+1: b0..b3,a0,a2 landed
            __builtin_amdgcn_s_barrier();
            __builtin_amdgcn_sched_barrier(0);
            const short* AbN = laN;
            const short* BbN = lbN;
#pragma unroll
            for (int i = 0; i < 4; ++i) { afA[i][0] = LDA_(AbN, 0, i, 0); afA[i][1] = LDA_(AbN, 0, i, 1); }
#pragma unroll
            for (int j = 0; j < 2; ++j) { b0[j][0] = LDB_(BbN, j, 0); b0[j][1] = LDB_(BbN, j, 1); }
        }
        __builtin_amdgcn_s_setprio(1);
#pragma unroll
        for (int i = 0; i < 4; ++i)
#pragma unroll
            for (int j = 0; j < 2; ++j) {
                acc[1][i][2 + j] = __builtin_amdgcn_mfma_f32_16x16x32_bf16(afB[i][0], b1[j][0], acc[1][i][2 + j], 0, 0, 0);
                acc[1][i][2 + j] = __builtin_amdgcn_mfma_f32_16x16x32_bf16(afB[i][1], b1[j][1], acc[1][i][2 + j], 0, 0, 0);
            }
        __builtin_amdgcn_s_setprio(0);
        __builtin_amdgcn_sched_barrier(0);
    }
#undef LDA_
#undef LDB_
#undef STAGE_A
#undef STAGE_B

    // epilogue: C/D layout row=fq*4+r, col=fr within 16x16 (m89-verified)
    if constexpr (MODE == 0) {
        __hip_bfloat16* O = (__hip_bfloat16*)outp;
        float bv[4];
#pragma unroll
        for (int j = 0; j < 4; ++j) {
            int gcol = n0 + wn + j * 16 + fr;
            bv[j] = (gcol < D_MODEL) ? bias0[gcol] : bias1[gcol - D_MODEL];
        }
#pragma unroll
        for (int h = 0; h < 2; ++h)
#pragma unroll
            for (int i = 0; i < 4; ++i)
#pragma unroll
                for (int r = 0; r < 4; ++r) {
                    int grow = m0 + wm + h * 64 + i * 16 + fq * 4 + r;
                    __hip_bfloat16* orow = O + (size_t)grow * N + n0 + wn + fr;
#pragma unroll
                    for (int j = 0; j < 4; ++j)
                        orow[j * 16] = __float2bfloat16(acc[h][i][j][r] + bv[j]);
                }
    } else {
        float* O = (float*)outp;
#pragma unroll
        for (int h = 0; h < 2; ++h)
#pragma unroll
            for (int i = 0; i < 4; ++i)
#pragma unroll
                for (int r = 0; r < 4; ++r) {
                    int grow = m0 + wm + h * 64 + i * 16 + fq * 4 + r;
#pragma unroll
                    for (int j = 0; j < 4; ++j) {
                        int gcol = n0 + wn + j * 16 + fr;
                        O[(size_t)grow * N + gcol] =
                            acc[h][i][j][r] + bias0[gcol] + bias1[(size_t)grow * D_MODEL + gcol];
                    }
                }
    }
}

// ---------------- chunked scan, pass 1 ----------------
__global__ __launch_bounds__(256) void scan_part1(
    const __hip_bfloat16* __restrict__ out1,
    float* __restrict__ Abuf, float* __restrict__ Bbuf)
{
    int g = blockIdx.x * 256 + threadIdx.x;
    int chan = g & (NCHAN - 1);
    int c = g >> 12;
    int b = chan >> 10;
    int hd = chan & 1023;
    int h = hd >> 6, d = hd & 63;
    size_t tok0 = (size_t)b * SEQ + (size_t)c * CLEN;
    const __hip_bfloat16* pd = out1 + tok0 * N1 + D_MODEL + h * 192 + d;
    float a = 1.0f, hloc = 0.0f;
#pragma unroll 4
    for (int s = 0; s < CLEN; s++) {
        float dp = __bfloat162float(pd[0]);
        float bt = __bfloat162float(pd[64]);
        float sd = sigmoidf_(dp);
        a *= sd;
        hloc = sd * hloc + bt;
        pd += N1;
    }
    Abuf[c * NCHAN + chan] = a;
    Bbuf[c * NCHAN + chan] = hloc;
}

// ---------------- scan, pass 2 ----------------
__global__ __launch_bounds__(256) void scan_comb(
    const float* __restrict__ Abuf, const float* __restrict__ Bbuf,
    const float* __restrict__ state, float* __restrict__ Pbuf,
    float* __restrict__ new_state)
{
    int chan = blockIdx.x * 256 + threadIdx.x;
    float hp = state[chan];
#pragma unroll
    for (int c = 0; c < NCH; c++) {
        Pbuf[c * NCHAN + chan] = hp;
        hp = Abuf[c * NCHAN + chan] * hp + Bbuf[c * NCHAN + chan];
    }
    new_state[chan] = hp;
}

// ---------------- scan, pass 3 ----------------
__global__ __launch_bounds__(256) void scan_apply(
    const __hip_bfloat16* __restrict__ out1,
    const __hip_bfloat16* __restrict__ xn,
    const float* __restrict__ Pbuf,
    __hip_bfloat16* __restrict__ mixed)
{
    int g = blockIdx.x * 256 + threadIdx.x;
    int chan = g & (NCHAN - 1);
    int c = g >> 12;
    int b = chan >> 10;
    int hd = chan & 1023;
    int h = hd >> 6, d = hd & 63;
    size_t tok0 = (size_t)b * SEQ + (size_t)c * CLEN;
    const __hip_bfloat16* rbase = out1 + tok0 * N1;
    const __hip_bfloat16* xbase = xn + tok0 * D_MODEL + hd;
    __hip_bfloat16* mbase = mixed + tok0 * D_MODEL + hd;
    const int pcol = D_MODEL + h * 192 + d;
    float hh = Pbuf[c * NCHAN + chan];
#pragma unroll 4
    for (int s = 0; s < CLEN; s++) {
        const __hip_bfloat16* r = rbase + (size_t)s * N1;
        float dp = __bfloat162float(r[pcol]);
        float bt = __bfloat162float(r[pcol + 64]);
        float ct = __bfloat162float(r[pcol + 128]);
        float gp = __bfloat162float(r[hd]);
        float sd = sigmoidf_(dp);
        hh = sd * hh + bt;
        float gg = sigmoidf_(gp);
        float xv = __bfloat162float(xbase[(size_t)s * D_MODEL]);
        mbase[(size_t)s * D_MODEL] = __float2bfloat16(gg * (ct * hh) + (1.0f - gg) * xv);
    }
}

extern "C" void kernel_launch(void* const* d_in, const int* in_sizes, int n_in,
                              void* d_out, int out_size, void* d_ws, size_t ws_size,
                              hipStream_t stream) {
    const float* x      = (const float*)d_in[0];
    const float* state  = (const float*)d_in[1];
    const float* norm_w = (const float*)d_in[2];
    const float* Wp     = (const float*)d_in[3];
    const float* bp     = (const float*)d_in[4];
    const float* Wg     = (const float*)d_in[5];
    const float* bg     = (const float*)d_in[6];
    const float* Wo     = (const float*)d_in[7];
    const float* bo     = (const float*)d_in[8];
    float* out = (float*)d_out;

    // workspace layout (~204 MB)
    __hip_bfloat16* W1T   = (__hip_bfloat16*)d_ws;                  // 4096 x 1024
    __hip_bfloat16* WoT   = W1T + (size_t)N1 * D_MODEL;             // 1024 x 1024
    __hip_bfloat16* xnb   = WoT + (size_t)D_MODEL * D_MODEL;        // 16384 x 1024
    __hip_bfloat16* out1  = xnb + (size_t)M_TOK * D_MODEL;          // 16384 x 4096
    __hip_bfloat16* mixed = out1 + (size_t)M_TOK * N1;              // 16384 x 1024
    float* Abuf = (float*)(mixed + (size_t)M_TOK * D_MODEL);
    float* Bbuf = Abuf + (size_t)NCHAN * NCH;
    float* Pbuf = Bbuf + (size_t)NCHAN * NCH;

    static bool attr_set = false;
    if (!attr_set) {
        hipFuncSetAttribute(reinterpret_cast<const void*>(&gemm256<0>),
                            hipFuncAttributeMaxDynamicSharedMemorySize, 131072);
        hipFuncSetAttribute(reinterpret_cast<const void*>(&gemm256<1>),
                            hipFuncAttributeMaxDynamicSharedMemorySize, 131072);
        attr_set = true;
    }

    dim3 tb(32, 8);
    transpose_cvt<<<dim3(1024 / 32, 1024 / 32), tb, 0, stream>>>(Wg, W1T, 1024, 1024);
    transpose_cvt<<<dim3(3072 / 32, 1024 / 32), tb, 0, stream>>>(
        Wp, W1T + (size_t)D_MODEL * D_MODEL, 1024, 3072);
    transpose_cvt<<<dim3(1024 / 32, 1024 / 32), tb, 0, stream>>>(Wo, WoT, 1024, 1024);

    rmsnorm_kernel<<<M_TOK, 256, 0, stream>>>(x, norm_w, xnb);

    gemm256<0><<<dim3(N1 / 256, M_TOK / 256), 512, 131072, stream>>>(
        xnb, W1T, bg, bp, (void*)out1, N1, D_MODEL);

    scan_part1<<<(NCHAN * NCH) / 256, 256, 0, stream>>>(out1, Abuf, Bbuf);
    scan_comb<<<NCHAN / 256, 256, 0, stream>>>(
        Abuf, Bbuf, state, Pbuf, out + (size_t)M_TOK * D_MODEL);
    scan_apply<<<(NCHAN * NCH) / 256, 256, 0, stream>>>(out1, xnb, Pbuf, mixed);

    gemm256<1><<<dim3(D_MODEL / 256, M_TOK / 256), 512, 131072, stream>>>(
        mixed, WoT, bo, x, (void*)out, D_MODEL, D_MODEL);
}